// Round 20
// baseline (318.884 us; speedup 1.0000x reference)
//
#include <hip/hip_runtime.h>
#include <stdint.h>

#define NN 6144        // nodes
#define NC 576         // padded V columns (517 used)

typedef float f32x4 __attribute__((ext_vector_type(4)));
typedef __bf16 bf16x8v __attribute__((ext_vector_type(8)));

__device__ __forceinline__ unsigned short f2bf(float f) {
  unsigned u = __float_as_uint(f);
  u += 0x7FFFu + ((u >> 16) & 1u);   // RNE
  return (unsigned short)(u >> 16);
}

__device__ __forceinline__ float bf2f(unsigned short s) {
  unsigned u = (unsigned)s << 16;
  return __uint_as_float(u);
}

// f32 -> OCP e4m3fn, RNE, clamp to +-448
__device__ __forceinline__ unsigned char f2e4m3(float f) {
  unsigned u = __float_as_uint(f);
  unsigned sgn = (u >> 24) & 0x80u;
  unsigned au = u & 0x7FFFFFFFu;
  if (au >= 0x43E00000u) return (unsigned char)(sgn | 0x7E);
  if (au < 0x3C800000u) {
    int q = (int)rintf(__uint_as_float(au) * 512.0f);
    return (unsigned char)(sgn | (q >= 8 ? 0x08 : q));
  }
  unsigned r = au + 0x7FFFFu + ((au >> 20) & 1u);
  int e = (int)(r >> 23) - 127;
  unsigned m = (r >> 20) & 7u;
  return (unsigned char)(sgn | ((unsigned)(e + 7) << 3) | m);
}

__device__ __forceinline__ unsigned short pack2(float a, float b) {
  return (unsigned short)f2e4m3(a) | ((unsigned short)f2e4m3(b) << 8);
}

__device__ __forceinline__ void async_load16(const void* g, void* l) {
  __builtin_amdgcn_global_load_lds(
      (__attribute__((address_space(1))) void*)(uintptr_t)g,
      (__attribute__((address_space(3))) void*)(uint32_t)(uintptr_t)l,
      16, 0, 0);
}

// ---------------- p0s: small prep (R13-verified, unchanged) ----------------
__global__ __launch_bounds__(256) void p0s(
    const float* __restrict__ x, const float* __restrict__ W,
    const float* __restrict__ Aw, const float* __restrict__ Wb,
    unsigned short* __restrict__ xsw, unsigned short* __restrict__ wsw,
    float* __restrict__ Acat, float* __restrict__ T)
{
  const int bid = blockIdx.x, t = threadIdx.x;
  if (bid < 8) {           // wsw: 8192 entries (16 col-tiles x 8 kc x 64 lanes)
#pragma unroll
    for (int i = 0; i < 4; ++i) {
      const int e = bid * 256 + t + i * 2048;
      const int l = e & 63, kc = (e >> 6) & 7, ct = e >> 9;
      const int c = ct * 16 + (l & 15);
      const int h = c >> 6, d0 = c & 63;
      const int ks = kc * 32 + (l >> 4) * 8;
      const float* src = W + h * 16384 + ks * 64 + d0;
      unsigned uu[4];
#pragma unroll
      for (int j = 0; j < 4; ++j)
        uu[j] = (unsigned)f2bf(src[(2*j) * 64]) | ((unsigned)f2bf(src[(2*j+1) * 64]) << 16);
      *(uint4*)(wsw + (size_t)e * 8) = (uint4){uu[0], uu[1], uu[2], uu[3]};
    }
    return;
  }
  if (bid == 8) {          // Acat[asv|adv|Wbc], T zero
    T[t] = 0.f;
    const int h = t >> 6, d = t & 63;
    Acat[t]       = Aw[h * 128 + d];
    Acat[256 + t] = Aw[h * 128 + 64 + d];
    Acat[512 + t] = Wb[t];
    return;
  }
  const int tid = (bid - 9) * 256 + t;   // xsw: 24 blocks
#pragma unroll 4
  for (int i = 0; i < 32; ++i) {
    const int e = tid + i * 6144;
    const int l = e & 63, kc = (e >> 6) & 7, mt = e >> 9;
    const int node = mt * 16 + (l & 15);
    const int ks = kc * 32 + (l >> 4) * 8;
    const float4* xp = (const float4*)(x + (size_t)node * 256 + ks);
    float4 v0 = xp[0], v1 = xp[1];
    uint4 o;
    o.x = (unsigned)f2bf(v0.x) | ((unsigned)f2bf(v0.y) << 16);
    o.y = (unsigned)f2bf(v0.z) | ((unsigned)f2bf(v0.w) << 16);
    o.z = (unsigned)f2bf(v1.x) | ((unsigned)f2bf(v1.y) << 16);
    o.w = (unsigned)f2bf(v1.z) | ((unsigned)f2bf(v1.w) << 16);
    *(uint4*)(xsw + (size_t)e * 8) = o;
  }
}

// ---------------- k1m: feature MFMA (blocks 0..191) + adj->fp8 pack (192..4799) (R18) --------
__global__ __launch_bounds__(256) void k1m(
    const unsigned short* __restrict__ xsw, const unsigned short* __restrict__ wsw,
    const float* __restrict__ Acat, const float* __restrict__ Ab,
    const int* __restrict__ adj, unsigned char* __restrict__ A8,
    unsigned char* __restrict__ V8, float* __restrict__ e_src, float* __restrict__ T)
{
  __shared__ unsigned char lv[4][4096];
  __shared__ float lt[256];
  const int t = threadIdx.x;

  if (blockIdx.x >= 192) {   // ---- pack: adj int32 -> fp8 (0x00 / 0x38) ----
    const int pb = blockIdx.x - 192;           // 0..4607
    const int4* a4 = (const int4*)adj;
    unsigned* o1 = (unsigned*)A8;
    const int g0 = pb * 2048 + t;
    int4 q[8];
#pragma unroll
    for (int j = 0; j < 8; ++j) q[j] = a4[g0 + j * 256];
#pragma unroll
    for (int j = 0; j < 8; ++j)
      o1[g0 + j * 256] = (unsigned)q[j].x * 0x38u | (unsigned)q[j].y * 0x3800u |
                         (unsigned)q[j].z * 0x380000u | (unsigned)q[j].w * 0x38000000u;
    return;
  }

  // ---- k1-part (R10-verified structure) ----
  const int w = t >> 6, l = t & 63;
  const int v = blockIdx.x * 4 + w;
  const int mt = v >> 1, nh = v & 1;
  const int i0 = mt * 16, c0 = nh * 128;
  const int lm = l & 15, lk = l >> 4;

  lt[t] = 0.f;
  __syncthreads();

  f32x4 acc[8];
#pragma unroll
  for (int nt = 0; nt < 8; ++nt) acc[nt] = (f32x4){0.f, 0.f, 0.f, 0.f};

  const unsigned short* ap = xsw + ((size_t)mt * 512 + l) * 8;
  const unsigned short* bp = wsw + ((size_t)nh * 4096 + l) * 8;

#pragma unroll
  for (int kc = 0; kc < 8; ++kc) {
    bf16x8v a = *(const bf16x8v*)(ap + (size_t)kc * 512);
#pragma unroll
    for (int nt = 0; nt < 8; ++nt) {
      bf16x8v b = *(const bf16x8v*)(bp + ((size_t)nt * 512 + kc * 64) * 8);
      acc[nt] = __builtin_amdgcn_mfma_f32_16x16x32_bf16(a, b, acc[nt], 0, 0, 0);
    }
  }

  float asv[8], adv[8];
#pragma unroll
  for (int nt = 0; nt < 8; ++nt) {
    const int cc = c0 + nt * 16 + lm;
    const float wb = Acat[512 + cc];
#pragma unroll
    for (int rr = 0; rr < 4; ++rr) acc[nt][rr] += wb;
    asv[nt] = Acat[cc];
    adv[nt] = Acat[256 + cc];
  }

#pragma unroll
  for (int nt = 0; nt < 8; ++nt)
    atomicAdd(&lt[c0 + nt * 16 + lm], acc[nt][0] + acc[nt][1] + acc[nt][2] + acc[nt][3]);

  float ss[2][4], sd[2][4];
#pragma unroll
  for (int hl = 0; hl < 2; ++hl)
#pragma unroll
    for (int rr = 0; rr < 4; ++rr) {
      float s1 = 0.f, s2 = 0.f;
#pragma unroll
      for (int j = 0; j < 4; ++j) {
        s1 += acc[hl * 4 + j][rr] * asv[hl * 4 + j];
        s2 += acc[hl * 4 + j][rr] * adv[hl * 4 + j];
      }
      ss[hl][rr] = s1; sd[hl][rr] = s2;
    }
#pragma unroll
  for (int off = 1; off < 16; off <<= 1)
#pragma unroll
    for (int hl = 0; hl < 2; ++hl)
#pragma unroll
      for (int rr = 0; rr < 4; ++rr) {
        ss[hl][rr] += __shfl_xor(ss[hl][rr], off);
        sd[hl][rr] += __shfl_xor(sd[hl][rr], off);
      }

  float ed[2][4];
#pragma unroll
  for (int hl = 0; hl < 2; ++hl)
#pragma unroll
    for (int rr = 0; rr < 4; ++rr) ed[hl][rr] = expf(sd[hl][rr]);

  if (lm == 0) {
#pragma unroll
    for (int hl = 0; hl < 2; ++hl) {
      const int hh = nh * 2 + hl;
      const float ab = Ab[hh];
#pragma unroll
      for (int rr = 0; rr < 4; ++rr)
        e_src[(size_t)hh * NN + i0 + lk * 4 + rr] = expf(ss[hl][rr] + ab);
    }
  }

  unsigned char* mylv = lv[w];
#pragma unroll
  for (int nt = 0; nt < 8; ++nt) {
    const int hl = nt >> 2;
    const int d = (nt & 3) * 16 + lm;
    const int lcE = hl * 128 + d;
    const int lcP = lcE + 64;
    *(unsigned short*)(mylv + lcE * 16 + lk * 4)     = pack2(ed[hl][0] * acc[nt][0], ed[hl][1] * acc[nt][1]);
    *(unsigned short*)(mylv + lcE * 16 + lk * 4 + 2) = pack2(ed[hl][2] * acc[nt][2], ed[hl][3] * acc[nt][3]);
    *(unsigned short*)(mylv + lcP * 16 + lk * 4)     = pack2(acc[nt][0], acc[nt][1]);
    *(unsigned short*)(mylv + lcP * 16 + lk * 4 + 2) = pack2(acc[nt][2], acc[nt][3]);
  }
#pragma unroll
  for (int j = 0; j < 4; ++j) {
    const int lc = j * 64 + l;
    uint4 val = *(const uint4*)(mylv + lc * 16);
    *(uint4*)(V8 + (size_t)(nh * 256 + lc) * NN + i0) = val;
  }
  if (lm == 0) {
#pragma unroll
    for (int hl = 0; hl < 2; ++hl) {
      const int hh = nh * 2 + hl;
      unsigned char* pq = V8 + (size_t)(512 + hh) * NN + i0 + lk * 4;
      *(unsigned short*)pq       = pack2(ed[hl][0], ed[hl][1]);
      *(unsigned short*)(pq + 2) = pack2(ed[hl][2], ed[hl][3]);
    }
    if (nh == 0)
      *(unsigned*)(V8 + (size_t)516 * NN + i0 + lk * 4) = 0x38383838u;
  }

  __syncthreads();
  atomicAdd(&T[t], lt[t]);
}

// ---------------- k2 v10: R18 structure; nks=12 (grid 1536 = 6 blocks/CU co-resident) --------
// tile 192x144, BK=128 — block-iter count invariant vs nks=6 (1536x4 = 768x8); the extra
// co-residency hides the two barrier drains per iter (m114 mechanism, R15-clean).
__global__ __launch_bounds__(256, 3) void k2_gemm(
    const unsigned char* __restrict__ A8, const unsigned char* __restrict__ V8,
    unsigned short* __restrict__ out2b, float* __restrict__ out2e, int nks)
{
  __shared__ unsigned char lB[144 * 128];
  const int t   = threadIdx.x;
  const int cb  = blockIdx.x & 3;
  const int rb  = (blockIdx.x >> 2) & 31;
  const int ks  = blockIdx.x >> 7;
  const int krange = NN / nks;
  const int i0 = rb * 192, n0 = cb * 144, k0 = ks * krange;
  const int w = t >> 6, l = t & 63;
  const int lm = l & 15, lk = l >> 4;

  f32x4 acc[3][9];
#pragma unroll
  for (int mt = 0; mt < 3; ++mt)
#pragma unroll
    for (int nt = 0; nt < 9; ++nt) acc[mt][nt] = (f32x4){0.f, 0.f, 0.f, 0.f};

  int scol[5], sgr[5];
#pragma unroll
  for (int u = 0; u < 5; ++u) {
    const int gi = u * 256 + t;
    scol[u] = gi >> 3;
    sgr[u]  = (gi & 7) ^ (scol[u] & 7);
  }
  const int dbase4 = (1024 + (t & ~63)) * 16;

  const unsigned char* gA0 = A8 + (size_t)(i0 + w * 48 + lm) * NN + k0 + lk * 32;
  const unsigned char* gBb = V8 + (size_t)n0 * NN + k0;

  const int iters = krange / 128;
  for (int it = 0; it < iters; ++it) {
    const unsigned char* gB = gBb + it * 128;
#pragma unroll
    for (int u = 0; u < 4; ++u)
      async_load16(gB + (size_t)scol[u] * NN + sgr[u] * 16,
                   (char*)lB + (size_t)(u * 256 + (t & ~63)) * 16);
    if (t < 128)
      async_load16(gB + (size_t)scol[4] * NN + sgr[4] * 16, (char*)lB + dbase4);
    longlong2 afr[3][2];
    const unsigned char* gA = gA0 + it * 128;
#pragma unroll
    for (int mt = 0; mt < 3; ++mt) {
      afr[mt][0] = *(const longlong2*)(gA + (size_t)mt * 16 * NN);
      afr[mt][1] = *(const longlong2*)(gA + (size_t)mt * 16 * NN + 16);
    }
    __syncthreads();
#pragma unroll
    for (int b = 0; b < 2; ++b) {
#pragma unroll
      for (int nt = 0; nt < 9; ++nt) {
        const int cc = nt * 16 + lm;
        const int pos = (lk * 2 + b) ^ (cc & 7);
        longlong2 bv = *(const longlong2*)(lB + cc * 128 + pos * 16);
#pragma unroll
        for (int mt = 0; mt < 3; ++mt) {
          acc[mt][nt] = __builtin_amdgcn_mfma_f32_16x16x32_fp8_fp8(
              afr[mt][b].x, bv.x, acc[mt][nt], 0, 0, 0);
          acc[mt][nt] = __builtin_amdgcn_mfma_f32_16x16x32_fp8_fp8(
              afr[mt][b].y, bv.y, acc[mt][nt], 0, 0, 0);
        }
      }
    }
    __syncthreads();
  }

  // epilogue: per-wave LDS transpose -> contiguous panel chunks (R18-verified)
  unsigned short* lw = (unsigned short*)(lB + w * 4608);
  float* oe = out2e + (size_t)ks * ((size_t)NN * 64);
  unsigned short* pb = out2b + ((size_t)(ks * 4 + cb) * NN + i0 + w * 48) * 144;
#pragma unroll
  for (int mt = 0; mt < 3; ++mt) {
#pragma unroll
    for (int nt = 0; nt < 9; ++nt) {
      const int coll = nt * 16 + lm;
#pragma unroll
      for (int rr = 0; rr < 4; ++rr)
        lw[(lk * 4 + rr) * 144 + coll] = f2bf(acc[mt][nt][rr]);
      if (cb == 3 && nt >= 5) {
        const int row = i0 + w * 48 + mt * 16 + lk * 4;
#pragma unroll
        for (int rr = 0; rr < 4; ++rr)
          oe[(size_t)(row + rr) * 64 + (n0 + coll - 512)] = acc[mt][nt][rr];
      }
    }
    const uint4* ls = (const uint4*)(lB + w * 4608);
    char* dst = (char*)(pb + (size_t)mt * 16 * 144);
    for (int s = l; s < 288; s += 64)
      *(uint4*)(dst + s * 16) = ls[s];
  }
}

// ---------------- k3: combine across nks K-partials (R18-verified; nks param) ----------------
__global__ __launch_bounds__(256) void k3_final(
    const unsigned short* __restrict__ out2b, const float* __restrict__ out2e,
    const float* __restrict__ e_src, const float* __restrict__ T,
    float* __restrict__ out, int nks)
{
  const int n = blockIdx.x, c = threadIdx.x;
  const int h = c >> 6, d = c & 63;
  const int cS = h * 128 + d, cP = cS + 64;
  const int cbS = cS / 144, ofS = cS % 144;
  const int cbP = cP / 144, ofP = cP % 144;
  float Se = 0.f, Sp = 0.f, E = 0.f, dg = 0.f;
  for (int s = 0; s < nks; ++s) {
    const unsigned short* base = out2b + (size_t)s * 4 * NN * 144;
    Se += bf2f(base[((size_t)cbS * NN + n) * 144 + ofS]);
    Sp += bf2f(base[((size_t)cbP * NN + n) * 144 + ofP]);
    const float* re = out2e + (size_t)s * NN * 64 + (size_t)n * 64;
    E  += re[h];
    dg += re[4];
  }
  float e = e_src[h * NN + n];
  float D = e * E + ((float)NN - dg);
  out[(size_t)n * 256 + c] = (e * Se + (T[c] - Sp)) / D;
}

extern "C" void kernel_launch(void* const* d_in, const int* in_sizes, int n_in,
                              void* d_out, int out_size, void* d_ws, size_t ws_size,
                              hipStream_t stream) {
  const float* x  = (const float*)d_in[0];
  const int*   adj= (const int*)d_in[1];
  const float* W  = (const float*)d_in[2];
  const float* Wb = (const float*)d_in[3];
  const float* Aw = (const float*)d_in[4];
  const float* Ab = (const float*)d_in[5];
  float* out = (float*)d_out;
  char* ws = (char*)d_ws;
  unsigned char* V8 = (unsigned char*)ws;                 // 3,538,944
  float* e_src = (float*)(ws + 3538944);                  // 98,304
  float* T     = (float*)(ws + 3637248);                  // 1,024
  float* Acat  = (float*)(ws + 3638272);                  // 3,072 (asv|adv|Wbc)
  unsigned short* wsw = (unsigned short*)(ws + 3641344);  // 131,072
  unsigned short* xsw = (unsigned short*)(ws + 3772416);  // 3,145,728
  unsigned char* A8   = (unsigned char*)(ws + 6918144);   // 37,748,736
  unsigned short* out2b = (unsigned short*)(ws + 44666880); // nks x 7,077,888 (panels)
  // out2e placed after the largest (nks=12) out2b footprint:
  float* out2e = (float*)(ws + 44666880 + 12ull * 7077888); // nks x 1,572,864

  const size_t slabB = (size_t)4 * NN * 144 * 2;   // 7,077,888 per ks
  const size_t slabE = (size_t)NN * 64 * 4;        // 1,572,864 per ks
  const size_t need12 = 44666880 + 12 * slabB + 12 * slabE;   // ~148.5 MB
  int nks = 2;
  if (ws_size >= need12)                                   nks = 12;  // grid 1536 = 6 blk/CU
  else if (ws_size >= 44666880 + 12 * slabB + 6 * slabE)   nks = 6;   // conservative fallback
  else if (ws_size >= 44666880 + 4 * slabB + 4 * slabE)    nks = 4;

  hipLaunchKernelGGL(p0s, dim3(33), dim3(256), 0, stream,
                     x, W, Aw, Wb, xsw, wsw, Acat, T);
  hipLaunchKernelGGL(k1m, dim3(4800), dim3(256), 0, stream,
                     xsw, wsw, Acat, Ab, adj, A8, V8, e_src, T);
  hipLaunchKernelGGL(k2_gemm, dim3(128 * nks), dim3(256), 0, stream, A8, V8, out2b, out2e, nks);
  hipLaunchKernelGGL(k3_final, dim3(NN), dim3(256), 0, stream, out2b, out2e, e_src, T, out, nks);
}

// Round 21
// 299.329 us; speedup vs baseline: 1.0653x; 1.0653x over previous
//
#include <hip/hip_runtime.h>
#include <stdint.h>

#define NN 6144        // nodes
#define NC 576         // padded V columns (517 used)

typedef float f32x4 __attribute__((ext_vector_type(4)));
typedef __bf16 bf16x8v __attribute__((ext_vector_type(8)));

__device__ __forceinline__ unsigned short f2bf(float f) {
  unsigned u = __float_as_uint(f);
  u += 0x7FFFu + ((u >> 16) & 1u);   // RNE
  return (unsigned short)(u >> 16);
}

__device__ __forceinline__ float bf2f(unsigned short s) {
  unsigned u = (unsigned)s << 16;
  return __uint_as_float(u);
}

// f32 -> OCP e4m3fn, RNE, clamp to +-448
__device__ __forceinline__ unsigned char f2e4m3(float f) {
  unsigned u = __float_as_uint(f);
  unsigned sgn = (u >> 24) & 0x80u;
  unsigned au = u & 0x7FFFFFFFu;
  if (au >= 0x43E00000u) return (unsigned char)(sgn | 0x7E);
  if (au < 0x3C800000u) {
    int q = (int)rintf(__uint_as_float(au) * 512.0f);
    return (unsigned char)(sgn | (q >= 8 ? 0x08 : q));
  }
  unsigned r = au + 0x7FFFFu + ((au >> 20) & 1u);
  int e = (int)(r >> 23) - 127;
  unsigned m = (r >> 20) & 7u;
  return (unsigned char)(sgn | ((unsigned)(e + 7) << 3) | m);
}

__device__ __forceinline__ unsigned short pack2(float a, float b) {
  return (unsigned short)f2e4m3(a) | ((unsigned short)f2e4m3(b) << 8);
}

__device__ __forceinline__ void async_load16(const void* g, void* l) {
  __builtin_amdgcn_global_load_lds(
      (__attribute__((address_space(1))) void*)(uintptr_t)g,
      (__attribute__((address_space(3))) void*)(uint32_t)(uintptr_t)l,
      16, 0, 0);
}

// ---------------- p0s: small prep (R13-verified) ----------------
__global__ __launch_bounds__(256) void p0s(
    const float* __restrict__ x, const float* __restrict__ W,
    const float* __restrict__ Aw, const float* __restrict__ Wb,
    unsigned short* __restrict__ xsw, unsigned short* __restrict__ wsw,
    float* __restrict__ Acat, float* __restrict__ T)
{
  const int bid = blockIdx.x, t = threadIdx.x;
  if (bid < 8) {           // wsw: 8192 entries (16 col-tiles x 8 kc x 64 lanes)
#pragma unroll
    for (int i = 0; i < 4; ++i) {
      const int e = bid * 256 + t + i * 2048;
      const int l = e & 63, kc = (e >> 6) & 7, ct = e >> 9;
      const int c = ct * 16 + (l & 15);
      const int h = c >> 6, d0 = c & 63;
      const int ks = kc * 32 + (l >> 4) * 8;
      const float* src = W + h * 16384 + ks * 64 + d0;
      unsigned uu[4];
#pragma unroll
      for (int j = 0; j < 4; ++j)
        uu[j] = (unsigned)f2bf(src[(2*j) * 64]) | ((unsigned)f2bf(src[(2*j+1) * 64]) << 16);
      *(uint4*)(wsw + (size_t)e * 8) = (uint4){uu[0], uu[1], uu[2], uu[3]};
    }
    return;
  }
  if (bid == 8) {          // Acat[asv|adv|Wbc], T zero
    T[t] = 0.f;
    const int h = t >> 6, d = t & 63;
    Acat[t]       = Aw[h * 128 + d];
    Acat[256 + t] = Aw[h * 128 + 64 + d];
    Acat[512 + t] = Wb[t];
    return;
  }
  const int tid = (bid - 9) * 256 + t;   // xsw: 24 blocks
#pragma unroll 4
  for (int i = 0; i < 32; ++i) {
    const int e = tid + i * 6144;
    const int l = e & 63, kc = (e >> 6) & 7, mt = e >> 9;
    const int node = mt * 16 + (l & 15);
    const int ks = kc * 32 + (l >> 4) * 8;
    const float4* xp = (const float4*)(x + (size_t)node * 256 + ks);
    float4 v0 = xp[0], v1 = xp[1];
    uint4 o;
    o.x = (unsigned)f2bf(v0.x) | ((unsigned)f2bf(v0.y) << 16);
    o.y = (unsigned)f2bf(v0.z) | ((unsigned)f2bf(v0.w) << 16);
    o.z = (unsigned)f2bf(v1.x) | ((unsigned)f2bf(v1.y) << 16);
    o.w = (unsigned)f2bf(v1.z) | ((unsigned)f2bf(v1.w) << 16);
    *(uint4*)(xsw + (size_t)e * 8) = o;
  }
}

// ---------------- k1m: feature MFMA (blocks 0..191) + adj->fp8 pack (192..4799) (R13/R18) ----
__global__ __launch_bounds__(256) void k1m(
    const unsigned short* __restrict__ xsw, const unsigned short* __restrict__ wsw,
    const float* __restrict__ Acat, const float* __restrict__ Ab,
    const int* __restrict__ adj, unsigned char* __restrict__ A8,
    unsigned char* __restrict__ V8, float* __restrict__ e_src, float* __restrict__ T)
{
  __shared__ unsigned char lv[4][4096];
  __shared__ float lt[256];
  const int t = threadIdx.x;

  if (blockIdx.x >= 192) {   // ---- pack: adj int32 -> fp8 (0x00 / 0x38) ----
    const int pb = blockIdx.x - 192;           // 0..4607
    const int4* a4 = (const int4*)adj;
    unsigned* o1 = (unsigned*)A8;
    const int g0 = pb * 2048 + t;
    int4 q[8];
#pragma unroll
    for (int j = 0; j < 8; ++j) q[j] = a4[g0 + j * 256];
#pragma unroll
    for (int j = 0; j < 8; ++j)
      o1[g0 + j * 256] = (unsigned)q[j].x * 0x38u | (unsigned)q[j].y * 0x3800u |
                         (unsigned)q[j].z * 0x380000u | (unsigned)q[j].w * 0x38000000u;
    return;
  }

  // ---- k1-part (R10-verified structure) ----
  const int w = t >> 6, l = t & 63;
  const int v = blockIdx.x * 4 + w;
  const int mt = v >> 1, nh = v & 1;
  const int i0 = mt * 16, c0 = nh * 128;
  const int lm = l & 15, lk = l >> 4;

  lt[t] = 0.f;
  __syncthreads();

  f32x4 acc[8];
#pragma unroll
  for (int nt = 0; nt < 8; ++nt) acc[nt] = (f32x4){0.f, 0.f, 0.f, 0.f};

  const unsigned short* ap = xsw + ((size_t)mt * 512 + l) * 8;
  const unsigned short* bp = wsw + ((size_t)nh * 4096 + l) * 8;

#pragma unroll
  for (int kc = 0; kc < 8; ++kc) {
    bf16x8v a = *(const bf16x8v*)(ap + (size_t)kc * 512);
#pragma unroll
    for (int nt = 0; nt < 8; ++nt) {
      bf16x8v b = *(const bf16x8v*)(bp + ((size_t)nt * 512 + kc * 64) * 8);
      acc[nt] = __builtin_amdgcn_mfma_f32_16x16x32_bf16(a, b, acc[nt], 0, 0, 0);
    }
  }

  float asv[8], adv[8];
#pragma unroll
  for (int nt = 0; nt < 8; ++nt) {
    const int cc = c0 + nt * 16 + lm;
    const float wb = Acat[512 + cc];
#pragma unroll
    for (int rr = 0; rr < 4; ++rr) acc[nt][rr] += wb;
    asv[nt] = Acat[cc];
    adv[nt] = Acat[256 + cc];
  }

#pragma unroll
  for (int nt = 0; nt < 8; ++nt)
    atomicAdd(&lt[c0 + nt * 16 + lm], acc[nt][0] + acc[nt][1] + acc[nt][2] + acc[nt][3]);

  float ss[2][4], sd[2][4];
#pragma unroll
  for (int hl = 0; hl < 2; ++hl)
#pragma unroll
    for (int rr = 0; rr < 4; ++rr) {
      float s1 = 0.f, s2 = 0.f;
#pragma unroll
      for (int j = 0; j < 4; ++j) {
        s1 += acc[hl * 4 + j][rr] * asv[hl * 4 + j];
        s2 += acc[hl * 4 + j][rr] * adv[hl * 4 + j];
      }
      ss[hl][rr] = s1; sd[hl][rr] = s2;
    }
#pragma unroll
  for (int off = 1; off < 16; off <<= 1)
#pragma unroll
    for (int hl = 0; hl < 2; ++hl)
#pragma unroll
      for (int rr = 0; rr < 4; ++rr) {
        ss[hl][rr] += __shfl_xor(ss[hl][rr], off);
        sd[hl][rr] += __shfl_xor(sd[hl][rr], off);
      }

  float ed[2][4];
#pragma unroll
  for (int hl = 0; hl < 2; ++hl)
#pragma unroll
    for (int rr = 0; rr < 4; ++rr) ed[hl][rr] = expf(sd[hl][rr]);

  if (lm == 0) {
#pragma unroll
    for (int hl = 0; hl < 2; ++hl) {
      const int hh = nh * 2 + hl;
      const float ab = Ab[hh];
#pragma unroll
      for (int rr = 0; rr < 4; ++rr)
        e_src[(size_t)hh * NN + i0 + lk * 4 + rr] = expf(ss[hl][rr] + ab);
    }
  }

  unsigned char* mylv = lv[w];
#pragma unroll
  for (int nt = 0; nt < 8; ++nt) {
    const int hl = nt >> 2;
    const int d = (nt & 3) * 16 + lm;
    const int lcE = hl * 128 + d;
    const int lcP = lcE + 64;
    *(unsigned short*)(mylv + lcE * 16 + lk * 4)     = pack2(ed[hl][0] * acc[nt][0], ed[hl][1] * acc[nt][1]);
    *(unsigned short*)(mylv + lcE * 16 + lk * 4 + 2) = pack2(ed[hl][2] * acc[nt][2], ed[hl][3] * acc[nt][3]);
    *(unsigned short*)(mylv + lcP * 16 + lk * 4)     = pack2(acc[nt][0], acc[nt][1]);
    *(unsigned short*)(mylv + lcP * 16 + lk * 4 + 2) = pack2(acc[nt][2], acc[nt][3]);
  }
#pragma unroll
  for (int j = 0; j < 4; ++j) {
    const int lc = j * 64 + l;
    uint4 val = *(const uint4*)(mylv + lc * 16);
    *(uint4*)(V8 + (size_t)(nh * 256 + lc) * NN + i0) = val;
  }
  if (lm == 0) {
#pragma unroll
    for (int hl = 0; hl < 2; ++hl) {
      const int hh = nh * 2 + hl;
      unsigned char* pq = V8 + (size_t)(512 + hh) * NN + i0 + lk * 4;
      *(unsigned short*)pq       = pack2(ed[hl][0], ed[hl][1]);
      *(unsigned short*)(pq + 2) = pack2(ed[hl][2], ed[hl][3]);
    }
    if (nh == 0)
      *(unsigned*)(V8 + (size_t)516 * NN + i0 + lk * 4) = 0x38383838u;
  }

  __syncthreads();
  atomicAdd(&T[t], lt[t]);
}

// ---------------- k2 v9: BK=128 K-loop + panel epilogue (R18-verified) ----------
__global__ __launch_bounds__(256, 3) void k2_gemm(
    const unsigned char* __restrict__ A8, const unsigned char* __restrict__ V8,
    unsigned short* __restrict__ out2b, float* __restrict__ out2e, int nks)
{
  __shared__ unsigned char lB[144 * 128];
  const int t   = threadIdx.x;
  const int cb  = blockIdx.x & 3;
  const int rb  = (blockIdx.x >> 2) & 31;
  const int ks  = blockIdx.x >> 7;
  const int krange = NN / nks;
  const int i0 = rb * 192, n0 = cb * 144, k0 = ks * krange;
  const int w = t >> 6, l = t & 63;
  const int lm = l & 15, lk = l >> 4;

  f32x4 acc[3][9];
#pragma unroll
  for (int mt = 0; mt < 3; ++mt)
#pragma unroll
    for (int nt = 0; nt < 9; ++nt) acc[mt][nt] = (f32x4){0.f, 0.f, 0.f, 0.f};

  int scol[5], sgr[5];
#pragma unroll
  for (int u = 0; u < 5; ++u) {
    const int gi = u * 256 + t;
    scol[u] = gi >> 3;
    sgr[u]  = (gi & 7) ^ (scol[u] & 7);
  }
  const int dbase4 = (1024 + (t & ~63)) * 16;

  const unsigned char* gA0 = A8 + (size_t)(i0 + w * 48 + lm) * NN + k0 + lk * 32;
  const unsigned char* gBb = V8 + (size_t)n0 * NN + k0;

  const int iters = krange / 128;
  for (int it = 0; it < iters; ++it) {
    const unsigned char* gB = gBb + it * 128;
#pragma unroll
    for (int u = 0; u < 4; ++u)
      async_load16(gB + (size_t)scol[u] * NN + sgr[u] * 16,
                   (char*)lB + (size_t)(u * 256 + (t & ~63)) * 16);
    if (t < 128)
      async_load16(gB + (size_t)scol[4] * NN + sgr[4] * 16, (char*)lB + dbase4);
    longlong2 afr[3][2];
    const unsigned char* gA = gA0 + it * 128;
#pragma unroll
    for (int mt = 0; mt < 3; ++mt) {
      afr[mt][0] = *(const longlong2*)(gA + (size_t)mt * 16 * NN);
      afr[mt][1] = *(const longlong2*)(gA + (size_t)mt * 16 * NN + 16);
    }
    __syncthreads();
#pragma unroll
    for (int b = 0; b < 2; ++b) {
#pragma unroll
      for (int nt = 0; nt < 9; ++nt) {
        const int cc = nt * 16 + lm;
        const int pos = (lk * 2 + b) ^ (cc & 7);
        longlong2 bv = *(const longlong2*)(lB + cc * 128 + pos * 16);
#pragma unroll
        for (int mt = 0; mt < 3; ++mt) {
          acc[mt][nt] = __builtin_amdgcn_mfma_f32_16x16x32_fp8_fp8(
              afr[mt][b].x, bv.x, acc[mt][nt], 0, 0, 0);
          acc[mt][nt] = __builtin_amdgcn_mfma_f32_16x16x32_fp8_fp8(
              afr[mt][b].y, bv.y, acc[mt][nt], 0, 0, 0);
        }
      }
    }
    __syncthreads();
  }

  // epilogue: per-wave LDS transpose -> contiguous panel chunks
  unsigned short* lw = (unsigned short*)(lB + w * 4608);
  float* oe = out2e + (size_t)ks * ((size_t)NN * 64);
  unsigned short* pb = out2b + ((size_t)(ks * 4 + cb) * NN + i0 + w * 48) * 144;
#pragma unroll
  for (int mt = 0; mt < 3; ++mt) {
#pragma unroll
    for (int nt = 0; nt < 9; ++nt) {
      const int coll = nt * 16 + lm;
#pragma unroll
      for (int rr = 0; rr < 4; ++rr)
        lw[(lk * 4 + rr) * 144 + coll] = f2bf(acc[mt][nt][rr]);
      if (cb == 3 && nt >= 5) {
        const int row = i0 + w * 48 + mt * 16 + lk * 4;
#pragma unroll
        for (int rr = 0; rr < 4; ++rr)
          oe[(size_t)(row + rr) * 64 + (n0 + coll - 512)] = acc[mt][nt][rr];
      }
    }
    const uint4* ls = (const uint4*)(lB + w * 4608);
    char* dst = (char*)(pb + (size_t)mt * 16 * 144);
    for (int s = l; s < 288; s += 64)
      *(uint4*)(dst + s * 16) = ls[s];
  }
}

// ---------------- k3: combine across nks K-partials (R18-verified) ----------------
__global__ __launch_bounds__(256) void k3_final(
    const unsigned short* __restrict__ out2b, const float* __restrict__ out2e,
    const float* __restrict__ e_src, const float* __restrict__ T,
    float* __restrict__ out, int nks)
{
  const int n = blockIdx.x, c = threadIdx.x;
  const int h = c >> 6, d = c & 63;
  const int cS = h * 128 + d, cP = cS + 64;
  const int cbS = cS / 144, ofS = cS % 144;
  const int cbP = cP / 144, ofP = cP % 144;
  float Se = 0.f, Sp = 0.f, E = 0.f, dg = 0.f;
  for (int s = 0; s < nks; ++s) {
    const unsigned short* base = out2b + (size_t)s * 4 * NN * 144;
    Se += bf2f(base[((size_t)cbS * NN + n) * 144 + ofS]);
    Sp += bf2f(base[((size_t)cbP * NN + n) * 144 + ofP]);
    const float* re = out2e + (size_t)s * NN * 64 + (size_t)n * 64;
    E  += re[h];
    dg += re[4];
  }
  float e = e_src[h * NN + n];
  float D = e * E + ((float)NN - dg);
  out[(size_t)n * 256 + c] = (e * Se + (T[c] - Sp)) / D;
}

extern "C" void kernel_launch(void* const* d_in, const int* in_sizes, int n_in,
                              void* d_out, int out_size, void* d_ws, size_t ws_size,
                              hipStream_t stream) {
  const float* x  = (const float*)d_in[0];
  const int*   adj= (const int*)d_in[1];
  const float* W  = (const float*)d_in[2];
  const float* Wb = (const float*)d_in[3];
  const float* Aw = (const float*)d_in[4];
  const float* Ab = (const float*)d_in[5];
  float* out = (float*)d_out;
  char* ws = (char*)d_ws;
  unsigned char* V8 = (unsigned char*)ws;                 // 3,538,944
  float* e_src = (float*)(ws + 3538944);                  // 98,304
  float* T     = (float*)(ws + 3637248);                  // 1,024
  float* Acat  = (float*)(ws + 3638272);                  // 3,072 (asv|adv|Wbc)
  unsigned short* wsw = (unsigned short*)(ws + 3641344);  // 131,072
  unsigned short* xsw = (unsigned short*)(ws + 3772416);  // 3,145,728
  unsigned char* A8   = (unsigned char*)(ws + 6918144);   // 37,748,736
  unsigned short* out2b = (unsigned short*)(ws + 44666880); // nks x 4 x 1,769,472 (panels)
  float* out2e = (float*)(ws + 87134208);                   // nks x 1,572,864

  const size_t slabB = (size_t)4 * NN * 144 * 2;   // 7,077,888 per ks
  const size_t slabE = (size_t)NN * 64 * 4;        // 1,572,864 per ks
  int nks = 2;
  if (ws_size >= 87134208 + 6 * slabE)                    nks = 6;
  else if (ws_size >= 44666880 + 4 * slabB + 4 * slabE)   nks = 4;

  hipLaunchKernelGGL(p0s, dim3(33), dim3(256), 0, stream,
                     x, W, Aw, Wb, xsw, wsw, Acat, T);
  hipLaunchKernelGGL(k1m, dim3(4800), dim3(256), 0, stream,
                     xsw, wsw, Acat, Ab, adj, A8, V8, e_src, T);
  hipLaunchKernelGGL(k2_gemm, dim3(128 * nks), dim3(256), 0, stream, A8, V8, out2b, out2e, nks);
  hipLaunchKernelGGL(k3_final, dim3(NN), dim3(256), 0, stream, out2b, out2e, e_src, T, out, nks);
}